// Round 1
// baseline (1047.542 us; speedup 1.0000x reference)
//
#include <hip/hip_runtime.h>
#include <math.h>

// ---------------- workspace layout (float offsets) ----------------
#define WS_CTX    0         // 8192   (B*C)
#define WS_HDN    8192      // 512    (B*16)
#define WS_BMAT   8704      // 3584   (56*64)
#define WS_FHR    12288     // 3136
#define WS_FHI    15424     // 3136
#define WS_DTR    18560     // 1792   (32*56)
#define WS_DTI    20352     // 1792
#define WS_BNSUM  22144     // 256
#define WS_BNSQ   22400     // 256
#define WS_SCALE  22656     // 256
#define WS_SHIFT  22912     // 256
#define WS_COEF   23168     // 1048576 (B*C*M*K)
#define WS_Y      1071744   // 25690112 (B*C*56*56)

// ---------------- constants builder (runs every call, ~1us) ----------------
__global__ void k_const(float* __restrict__ Bmat, float* __restrict__ FhR,
                        float* __restrict__ FhI, float* __restrict__ DtR,
                        float* __restrict__ DtI) {
  const int idx = blockIdx.x * 256 + threadIdx.x;
  const double PI2 = 6.283185307179586476925286766559;
  if (idx < 3584) {
    // Bmat[w][vv]: vv<32 -> Re, vv>=32 -> Im.  (resize 56->62) then rfft_62.
    const int w  = idx >> 6;
    const int vv = idx & 63;
    const int v  = vv & 31;
    const bool isI = vv >= 32;
    double accR = 0.0, accI = 0.0;
    for (int wp = 0; wp < 62; ++wp) {
      const double src = (wp + 0.5) * (56.0 / 62.0) - 0.5;
      const int w0 = (int)floor(src);
      const double f = src - (double)w0;
      const double s0 = (w0 >= 0 && w0 <= 55) ? (1.0 - f) : 0.0;
      const double s1 = (w0 + 1 >= 0 && w0 + 1 <= 55) ? f : 0.0;
      const double ssum = s0 + s1;
      double wgt = 0.0;
      if (w == w0) wgt = s0 / ssum;
      else if (w == w0 + 1) wgt = s1 / ssum;
      if (wgt != 0.0) {
        const int p = (v * wp) % 62;
        const double ang = PI2 * (double)p / 62.0;
        accR += wgt * cos(ang);
        accI -= wgt * sin(ang);
      }
    }
    const double nrm = 1.0 / sqrt(3472.0);  // 1/sqrt(56*62), fwd ortho
    Bmat[idx] = (float)((isI ? accI : accR) * nrm);
  } else if (idx < 6720) {
    // Fh[u][h] = exp(-i*2*pi*u*h/56): FhR=cos, FhI=-sin (symmetric matrices)
    const int t = idx - 3584;
    const int u = t / 56, h = t % 56;
    const int a = (u * h) % 56;
    const double ang = PI2 * (double)a / 56.0;
    FhR[t] = (float)cos(ang);
    FhI[t] = (float)(-sin(ang));
  } else if (idx < 8512) {
    // Dt[v][w'']: C2R_62 (cv-weighted, DC/Nyq imag ignored) then antialiased
    // bilinear resize 62->56, inverse ortho norm folded in.
    const int t = idx - 6720;
    const int v = t / 56, wq = t % 56;
    const double ks = 62.0 / 56.0;  // antialias kernel scale (downsample)
    const double src = (wq + 0.5) * ks - 0.5;
    double wsum = 0.0;
    for (int wp = 0; wp < 62; ++wp) {
      const double xx = fabs(src - (double)wp) / ks;
      if (xx < 1.0) wsum += 1.0 - xx;
    }
    const double cv = (v == 0 || v == 31) ? 1.0 : 2.0;
    double accR = 0.0, accI = 0.0;
    for (int wp = 0; wp < 62; ++wp) {
      const double xx = fabs(src - (double)wp) / ks;
      if (xx >= 1.0) continue;
      const double wgt = (1.0 - xx) / wsum;
      double cc, ss;
      if (v == 0)       { cc = 1.0; ss = 0.0; }
      else if (v == 31) { cc = (wp & 1) ? -1.0 : 1.0; ss = 0.0; }
      else {
        const int p = (v * wp) % 62;
        const double ang = PI2 * (double)p / 62.0;
        cc = cos(ang); ss = sin(ang);
      }
      accR += wgt * cv * cc;
      accI -= wgt * cv * ss;
    }
    const double nrm = 1.0 / sqrt(3472.0);  // inverse ortho norm
    DtR[t] = (float)(accR * nrm);
    DtI[t] = (float)(accI * nrm);
  }
}

// ---------------- GAP: ctx[b,c] = mean_{h,w} x ----------------
__global__ __launch_bounds__(256) void k_gap(const float* __restrict__ x,
                                             float* __restrict__ ctx) {
  const int img = blockIdx.x;  // b*256+c
  const int tid = threadIdx.x;
  const float4* p4 = (const float4*)(x + (size_t)img * 3136);
  float s = 0.f;
  for (int i = tid; i < 784; i += 256) {
    const float4 v = p4[i];
    s += v.x + v.y + v.z + v.w;
  }
  for (int off = 32; off > 0; off >>= 1) s += __shfl_down(s, off, 64);
  __shared__ float ls[4];
  if ((tid & 63) == 0) ls[tid >> 6] = s;
  __syncthreads();
  if (tid == 0) ctx[img] = (ls[0] + ls[1] + ls[2] + ls[3]) * (1.0f / 3136.0f);
}

// ---------------- fc1 + LayerNorm + ReLU ----------------
__global__ void k_mlp(const float* __restrict__ ctx, const float* __restrict__ fc1_w,
                      const float* __restrict__ fc1_b, const float* __restrict__ ln_g,
                      const float* __restrict__ ln_b, float* __restrict__ hdn) {
  const int b = blockIdx.x;
  const int j = threadIdx.x;
  __shared__ float h[16];
  if (j < 16) {
    const float* cr = ctx + b * 256;
    const float* wr = fc1_w + j * 256;
    float acc = fc1_b[j];
    for (int c0 = 0; c0 < 256; ++c0) acc = fmaf(cr[c0], wr[c0], acc);
    h[j] = acc;
  }
  __syncthreads();
  if (j < 16) {
    float mu = 0.f, m2 = 0.f;
    for (int t = 0; t < 16; ++t) { mu += h[t]; m2 += h[t] * h[t]; }
    mu *= 0.0625f; m2 *= 0.0625f;
    const float var = m2 - mu * mu;
    const float val = (h[j] - mu) / sqrtf(var + 1e-5f) * ln_g[j] + ln_b[j];
    hdn[b * 16 + j] = fmaxf(val, 0.f);
  }
}

// ---------------- fourier head + softmax -> coeffs (B,C,M,K) ----------------
__global__ __launch_bounds__(256) void k_coeffs(const float* __restrict__ hdn,
                                                const float* __restrict__ fh_w,
                                                const float* __restrict__ fh_b,
                                                float* __restrict__ coeffs) {
  const int gid = blockIdx.x * 256 + threadIdx.x;  // (b, c*16+m), 131072 total
  const int b = gid >> 12;
  const int cm = gid & 4095;
  float hv[16];
  const float* hp = hdn + b * 16;
#pragma unroll
  for (int j = 0; j < 16; ++j) hv[j] = hp[j];
  const int row0 = cm * 8;  // = c*M*K + m*K
  float a[8];
  float mx = -1e30f;
#pragma unroll
  for (int k = 0; k < 8; ++k) {
    const float* wr = fh_w + (size_t)(row0 + k) * 16;
    float acc = fh_b[row0 + k];
#pragma unroll
    for (int j = 0; j < 16; ++j) acc = fmaf(hv[j], wr[j], acc);
    a[k] = acc;
    mx = fmaxf(mx, acc);
  }
  float s = 0.f;
#pragma unroll
  for (int k = 0; k < 8; ++k) { a[k] = expf(a[k] - mx); s += a[k]; }
  const float inv = 1.f / s;
  float* outp = coeffs + (size_t)gid * 8;
#pragma unroll
  for (int k = 0; k < 8; ++k) outp[k] = a[k] * inv;
}

// ---------------- fused resize+rfft2+filter+irfft2+resize per (b,c) ----------------
__global__ __launch_bounds__(256) void k_fft(
    const float* __restrict__ x, const float* __restrict__ coeffs,
    const float* __restrict__ basR, const float* __restrict__ basI,
    const float* __restrict__ Bmat, const float* __restrict__ FhR,
    const float* __restrict__ FhI, const float* __restrict__ DtR,
    const float* __restrict__ DtI, float* __restrict__ y) {
  __shared__ __align__(16) float xs[3136];  // input image
  __shared__ __align__(16) float x1[3584];  // [h][64]: Re v<32 | Im v>=32 ; reused for T
  __shared__ __align__(16) float yf[3584];  // [u][64] filtered spectrum
  const int img = blockIdx.x;
  const int tid = threadIdx.x;

  {  // load image
    const float4* xp = (const float4*)(x + (size_t)img * 3136);
    float4* xd = (float4*)xs;
    for (int i = tid; i < 784; i += 256) xd[i] = xp[i];
  }
  __syncthreads();

  // (b) x1 = xs @ Bmat : 56x56 @ 56x64
  for (int q = tid; q < 896; q += 256) {
    const int h = q >> 4;
    const int v4 = (q & 15) << 2;
    const float* xrow = xs + h * 56;
    const float* bp = Bmat + v4;
    float4 acc = make_float4(0.f, 0.f, 0.f, 0.f);
    for (int w = 0; w < 56; ++w) {
      const float xv = xrow[w];
      const float4 bm = *(const float4*)(bp + w * 64);
      acc.x = fmaf(xv, bm.x, acc.x);
      acc.y = fmaf(xv, bm.y, acc.y);
      acc.z = fmaf(xv, bm.z, acc.z);
      acc.w = fmaf(xv, bm.w, acc.w);
    }
    *(float4*)(x1 + h * 64 + v4) = acc;
  }
  __syncthreads();

  // (c) X = Fh @ x1 (complex), then multiply by G -> yf
  for (int q = tid; q < 448; q += 256) {
    const int u = q >> 3;
    const int v4 = (q & 7) << 2;
    float4 aR = make_float4(0.f, 0.f, 0.f, 0.f);
    float4 aI = make_float4(0.f, 0.f, 0.f, 0.f);
    const float* frp = FhR + u * 56;
    const float* fip = FhI + u * 56;
    for (int h = 0; h < 56; ++h) {
      const float fr = frp[h];
      const float fi = fip[h];
      const float4 xr = *(const float4*)(x1 + h * 64 + v4);
      const float4 xi = *(const float4*)(x1 + h * 64 + 32 + v4);
      aR.x = fmaf(fr, xr.x, aR.x); aR.x = fmaf(-fi, xi.x, aR.x);
      aR.y = fmaf(fr, xr.y, aR.y); aR.y = fmaf(-fi, xi.y, aR.y);
      aR.z = fmaf(fr, xr.z, aR.z); aR.z = fmaf(-fi, xi.z, aR.z);
      aR.w = fmaf(fr, xr.w, aR.w); aR.w = fmaf(-fi, xi.w, aR.w);
      aI.x = fmaf(fr, xi.x, aI.x); aI.x = fmaf(fi, xr.x, aI.x);
      aI.y = fmaf(fr, xi.y, aI.y); aI.y = fmaf(fi, xr.y, aI.y);
      aI.z = fmaf(fr, xi.z, aI.z); aI.z = fmaf(fi, xr.z, aI.z);
      aI.w = fmaf(fr, xi.w, aI.w); aI.w = fmaf(fi, xr.w, aI.w);
    }
    // filter G = sum_k coeffs[img,m,k] * basis[k,u,v]
    const int m = (u / 14) * 4 + (v4 >> 3);
    const float* co = coeffs + ((size_t)img * 16 + m) * 8;
    float4 gR = make_float4(0.f, 0.f, 0.f, 0.f);
    float4 gI = make_float4(0.f, 0.f, 0.f, 0.f);
#pragma unroll
    for (int k = 0; k < 8; ++k) {
      const float ck = co[k];
      const float4 br = *(const float4*)(basR + (k * 56 + u) * 32 + v4);
      const float4 bi = *(const float4*)(basI + (k * 56 + u) * 32 + v4);
      gR.x = fmaf(ck, br.x, gR.x); gR.y = fmaf(ck, br.y, gR.y);
      gR.z = fmaf(ck, br.z, gR.z); gR.w = fmaf(ck, br.w, gR.w);
      gI.x = fmaf(ck, bi.x, gI.x); gI.y = fmaf(ck, bi.y, gI.y);
      gI.z = fmaf(ck, bi.z, gI.z); gI.w = fmaf(ck, bi.w, gI.w);
    }
    float4 oR, oI;
    oR.x = aR.x * gR.x - aI.x * gI.x;  oI.x = aR.x * gI.x + aI.x * gR.x;
    oR.y = aR.y * gR.y - aI.y * gI.y;  oI.y = aR.y * gI.y + aI.y * gR.y;
    oR.z = aR.z * gR.z - aI.z * gI.z;  oI.z = aR.z * gI.z + aI.z * gR.z;
    oR.w = aR.w * gR.w - aI.w * gI.w;  oI.w = aR.w * gI.w + aI.w * gR.w;
    *(float4*)(yf + u * 64 + v4) = oR;
    *(float4*)(yf + u * 64 + 32 + v4) = oI;
  }
  __syncthreads();

  // (d) T = iFh @ yf (exp(+i..) = FhR - i*FhI, symmetric) -> x1
  for (int q = tid; q < 448; q += 256) {
    const int h = q >> 3;
    const int v4 = (q & 7) << 2;
    float4 tR = make_float4(0.f, 0.f, 0.f, 0.f);
    float4 tI = make_float4(0.f, 0.f, 0.f, 0.f);
    const float* frp = FhR + h * 56;
    const float* fip = FhI + h * 56;
    for (int u = 0; u < 56; ++u) {
      const float fr = frp[u];
      const float fi = fip[u];
      const float4 yr = *(const float4*)(yf + u * 64 + v4);
      const float4 yi = *(const float4*)(yf + u * 64 + 32 + v4);
      tR.x = fmaf(fr, yr.x, tR.x); tR.x = fmaf(fi, yi.x, tR.x);
      tR.y = fmaf(fr, yr.y, tR.y); tR.y = fmaf(fi, yi.y, tR.y);
      tR.z = fmaf(fr, yr.z, tR.z); tR.z = fmaf(fi, yi.z, tR.z);
      tR.w = fmaf(fr, yr.w, tR.w); tR.w = fmaf(fi, yi.w, tR.w);
      tI.x = fmaf(fr, yi.x, tI.x); tI.x = fmaf(-fi, yr.x, tI.x);
      tI.y = fmaf(fr, yi.y, tI.y); tI.y = fmaf(-fi, yr.y, tI.y);
      tI.z = fmaf(fr, yi.z, tI.z); tI.z = fmaf(-fi, yr.z, tI.z);
      tI.w = fmaf(fr, yi.w, tI.w); tI.w = fmaf(-fi, yr.w, tI.w);
    }
    *(float4*)(x1 + h * 64 + v4) = tR;
    *(float4*)(x1 + h * 64 + 32 + v4) = tI;
  }
  __syncthreads();

  // (e) y[h][w''] = sum_v DtR[v][w'']*Re T + DtI[v][w'']*Im T
  float* yo = y + (size_t)img * 3136;
  for (int q = tid; q < 784; q += 256) {
    const int h = q / 14;
    const int w4 = (q % 14) * 4;
    float4 acc = make_float4(0.f, 0.f, 0.f, 0.f);
    const float* trow = x1 + h * 64;
    for (int v = 0; v < 32; ++v) {
      const float tr = trow[v];
      const float ti = trow[32 + v];
      const float4 dr = *(const float4*)(DtR + v * 56 + w4);
      const float4 di = *(const float4*)(DtI + v * 56 + w4);
      acc.x = fmaf(tr, dr.x, acc.x); acc.x = fmaf(ti, di.x, acc.x);
      acc.y = fmaf(tr, dr.y, acc.y); acc.y = fmaf(ti, di.y, acc.y);
      acc.z = fmaf(tr, dr.z, acc.z); acc.z = fmaf(ti, di.z, acc.z);
      acc.w = fmaf(tr, dr.w, acc.w); acc.w = fmaf(ti, di.w, acc.w);
    }
    *(float4*)(yo + h * 56 + w4) = acc;
  }
}

// ---------------- 1x1 conv (GEMM) + BN partial sums ----------------
__global__ __launch_bounds__(256) void k_conv(const float* __restrict__ y,
                                              const float* __restrict__ cw,
                                              float* __restrict__ z,
                                              float* __restrict__ bnsum,
                                              float* __restrict__ bnsq) {
  __shared__ __align__(16) float Ws[16 * 68];
  __shared__ __align__(16) float Ys[16 * 68];
  const int pt = blockIdx.x * 64;
  const int ot = blockIdx.y * 64;
  const int b = blockIdx.z;
  const int tid = threadIdx.x;
  const int p4 = (tid & 15) << 2;
  const int o4 = (tid >> 4) << 2;
  float acc[4][4];
#pragma unroll
  for (int i = 0; i < 4; ++i)
#pragma unroll
    for (int j = 0; j < 4; ++j) acc[i][j] = 0.f;

  const float* yb = y + (size_t)b * 256 * 3136 + pt;
  const int wo = tid >> 2;
  const int wk = (tid & 3) << 2;
  const int yk = tid >> 4;
  const int yp = (tid & 15) << 2;

  for (int k0 = 0; k0 < 256; k0 += 16) {
    const float4 wv = *(const float4*)(cw + (size_t)(ot + wo) * 256 + k0 + wk);
    Ws[(wk + 0) * 68 + wo] = wv.x;
    Ws[(wk + 1) * 68 + wo] = wv.y;
    Ws[(wk + 2) * 68 + wo] = wv.z;
    Ws[(wk + 3) * 68 + wo] = wv.w;
    const float4 yv = *(const float4*)(yb + (size_t)(k0 + yk) * 3136 + yp);
    *(float4*)(Ys + yk * 68 + yp) = yv;
    __syncthreads();
#pragma unroll
    for (int kk = 0; kk < 16; ++kk) {
      const float4 w4v = *(const float4*)(Ws + kk * 68 + o4);
      const float4 y4v = *(const float4*)(Ys + kk * 68 + p4);
      acc[0][0] = fmaf(w4v.x, y4v.x, acc[0][0]);
      acc[0][1] = fmaf(w4v.x, y4v.y, acc[0][1]);
      acc[0][2] = fmaf(w4v.x, y4v.z, acc[0][2]);
      acc[0][3] = fmaf(w4v.x, y4v.w, acc[0][3]);
      acc[1][0] = fmaf(w4v.y, y4v.x, acc[1][0]);
      acc[1][1] = fmaf(w4v.y, y4v.y, acc[1][1]);
      acc[1][2] = fmaf(w4v.y, y4v.z, acc[1][2]);
      acc[1][3] = fmaf(w4v.y, y4v.w, acc[1][3]);
      acc[2][0] = fmaf(w4v.z, y4v.x, acc[2][0]);
      acc[2][1] = fmaf(w4v.z, y4v.y, acc[2][1]);
      acc[2][2] = fmaf(w4v.z, y4v.z, acc[2][2]);
      acc[2][3] = fmaf(w4v.z, y4v.w, acc[2][3]);
      acc[3][0] = fmaf(w4v.w, y4v.x, acc[3][0]);
      acc[3][1] = fmaf(w4v.w, y4v.y, acc[3][1]);
      acc[3][2] = fmaf(w4v.w, y4v.z, acc[3][2]);
      acc[3][3] = fmaf(w4v.w, y4v.w, acc[3][3]);
    }
    __syncthreads();
  }

  float s[4], s2[4];
#pragma unroll
  for (int i = 0; i < 4; ++i) {
    const float4 r = make_float4(acc[i][0], acc[i][1], acc[i][2], acc[i][3]);
    *(float4*)(z + ((size_t)b * 256 + ot + o4 + i) * 3136 + pt + p4) = r;
    s[i] = r.x + r.y + r.z + r.w;
    s2[i] = r.x * r.x + r.y * r.y + r.z * r.z + r.w * r.w;
  }
#pragma unroll
  for (int mask = 1; mask < 16; mask <<= 1) {
#pragma unroll
    for (int i = 0; i < 4; ++i) {
      s[i] += __shfl_xor(s[i], mask, 64);
      s2[i] += __shfl_xor(s2[i], mask, 64);
    }
  }
  if ((tid & 15) == 0) {
#pragma unroll
    for (int i = 0; i < 4; ++i) {
      atomicAdd(bnsum + ot + o4 + i, s[i]);
      atomicAdd(bnsq + ot + o4 + i, s2[i]);
    }
  }
}

// ---------------- BN stats finalize ----------------
__global__ void k_bnstats(const float* __restrict__ bnsum, const float* __restrict__ bnsq,
                          const float* __restrict__ bn_g, const float* __restrict__ bn_b,
                          float* __restrict__ scale, float* __restrict__ shift) {
  const int o = threadIdx.x;
  if (o < 256) {
    const float N = 32.f * 3136.f;
    const float m = bnsum[o] / N;
    const float v = bnsq[o] / N - m * m;
    const float sc = bn_g[o] / sqrtf(v + 1e-5f);
    scale[o] = sc;
    shift[o] = bn_b[o] - m * sc;
  }
}

// ---------------- BN apply (in-place on d_out) ----------------
__global__ __launch_bounds__(256) void k_bnapply(float* __restrict__ z,
                                                 const float* __restrict__ scale,
                                                 const float* __restrict__ shift) {
  const size_t i = ((size_t)blockIdx.x * 256 + threadIdx.x) * 4;
  const int ch = (int)((i / 3136) & 255);
  const float sc = scale[ch], sh = shift[ch];
  float4 v = *(float4*)(z + i);
  v.x = fmaf(v.x, sc, sh);
  v.y = fmaf(v.y, sc, sh);
  v.z = fmaf(v.z, sc, sh);
  v.w = fmaf(v.w, sc, sh);
  *(float4*)(z + i) = v;
}

extern "C" void kernel_launch(void* const* d_in, const int* in_sizes, int n_in,
                              void* d_out, int out_size, void* d_ws, size_t ws_size,
                              hipStream_t stream) {
  const float* x          = (const float*)d_in[0];
  const float* fc1_w      = (const float*)d_in[1];
  const float* fc1_b      = (const float*)d_in[2];
  const float* ln_g       = (const float*)d_in[3];
  const float* ln_b       = (const float*)d_in[4];
  const float* fh_w       = (const float*)d_in[5];
  const float* fh_b       = (const float*)d_in[6];
  const float* basis_real = (const float*)d_in[7];
  const float* basis_imag = (const float*)d_in[8];
  const float* conv_w     = (const float*)d_in[9];
  const float* bn_g       = (const float*)d_in[10];
  const float* bn_b       = (const float*)d_in[11];
  float* out = (float*)d_out;
  float* ws = (float*)d_ws;
  (void)in_sizes; (void)n_in; (void)out_size; (void)ws_size;

  hipMemsetAsync(ws + WS_BNSUM, 0, 512 * sizeof(float), stream);

  hipLaunchKernelGGL(k_const, dim3(34), dim3(256), 0, stream,
                     ws + WS_BMAT, ws + WS_FHR, ws + WS_FHI, ws + WS_DTR, ws + WS_DTI);
  hipLaunchKernelGGL(k_gap, dim3(8192), dim3(256), 0, stream, x, ws + WS_CTX);
  hipLaunchKernelGGL(k_mlp, dim3(32), dim3(64), 0, stream,
                     ws + WS_CTX, fc1_w, fc1_b, ln_g, ln_b, ws + WS_HDN);
  hipLaunchKernelGGL(k_coeffs, dim3(512), dim3(256), 0, stream,
                     ws + WS_HDN, fh_w, fh_b, ws + WS_COEF);
  hipLaunchKernelGGL(k_fft, dim3(8192), dim3(256), 0, stream,
                     x, ws + WS_COEF, basis_real, basis_imag, ws + WS_BMAT,
                     ws + WS_FHR, ws + WS_FHI, ws + WS_DTR, ws + WS_DTI, ws + WS_Y);
  hipLaunchKernelGGL(k_conv, dim3(49, 4, 32), dim3(256), 0, stream,
                     ws + WS_Y, conv_w, out, ws + WS_BNSUM, ws + WS_BNSQ);
  hipLaunchKernelGGL(k_bnstats, dim3(1), dim3(256), 0, stream,
                     ws + WS_BNSUM, ws + WS_BNSQ, bn_g, bn_b, ws + WS_SCALE, ws + WS_SHIFT);
  hipLaunchKernelGGL(k_bnapply, dim3(25088), dim3(256), 0, stream,
                     out, ws + WS_SCALE, ws + WS_SHIFT);
}

// Round 2
// 713.040 us; speedup vs baseline: 1.4691x; 1.4691x over previous
//
#include <hip/hip_runtime.h>
#include <math.h>

typedef __attribute__((ext_vector_type(4))) float f32x4;
typedef __attribute__((ext_vector_type(8))) short s16x8;
typedef __attribute__((ext_vector_type(4))) short s16x4;
typedef unsigned short ushort_t;

#define MFMA16(a, b, c) __builtin_amdgcn_mfma_f32_16x16x32_bf16((a), (b), (c), 0, 0, 0)

// ---------------- workspace byte offsets ----------------
#define WO_CTX    0u          // 32768
#define WO_HDN    32768u      // 2048
#define WO_BNSUM  34816u      // 1024
#define WO_BNSQ   35840u      // 1024
#define WO_SCALE  36864u      // 1024
#define WO_SHIFT  37888u      // 1024
#define WO_COEF   40960u      // 4194304
#define WO_BMT_H  4235264u    // 8192  (64x64 bf16)
#define WO_BMT_L  4243456u
#define WO_FARE_H 4251648u    // 16384 (64x128)
#define WO_FARE_L 4268032u
#define WO_FAIM_H 4284416u
#define WO_FAIM_L 4300800u
#define WO_FDRE_H 4317184u
#define WO_FDRE_L 4333568u
#define WO_FDIM_H 4349952u
#define WO_FDIM_L 4366336u
#define WO_DTT_H  4382720u    // 8192 (64x64)
#define WO_DTT_L  4390912u
#define WO_CW_H   4399104u    // 131072 (256x256)
#define WO_CW_L   4530176u
#define WO_YBF    4661248u    // 51380224 (8192*3136 bf16)

__device__ __forceinline__ ushort_t f2bf(float f) {
  unsigned int u = __builtin_bit_cast(unsigned int, f);
  unsigned int r = (u + 0x7fffu + ((u >> 16) & 1u)) >> 16;
  return (ushort_t)r;
}
__device__ __forceinline__ float bf2f(ushort_t h) {
  unsigned int u = ((unsigned int)h) << 16;
  return __builtin_bit_cast(float, u);
}

// ---------------- constant-matrix math (double precision) ----------------
__device__ double bmat_val(int w, int vv) {
  // column vv of (resize56->62 then rfft62, fwd ortho): vv<32 Re, else Im
  const int v = vv & 31;
  const bool isI = vv >= 32;
  double accR = 0.0, accI = 0.0;
  for (int wp = 0; wp < 62; ++wp) {
    const double src = (wp + 0.5) * (56.0 / 62.0) - 0.5;
    const int w0 = (int)floor(src);
    const double f = src - (double)w0;
    const double s0 = (w0 >= 0 && w0 <= 55) ? (1.0 - f) : 0.0;
    const double s1 = (w0 + 1 >= 0 && w0 + 1 <= 55) ? f : 0.0;
    const double ssum = s0 + s1;
    double wgt = 0.0;
    if (w == w0) wgt = s0 / ssum;
    else if (w == w0 + 1) wgt = s1 / ssum;
    if (wgt != 0.0) {
      const int p = (v * wp) % 62;
      const double ang = 6.283185307179586476925286766559 * (double)p / 62.0;
      accR += wgt * cos(ang);
      accI -= wgt * sin(ang);
    }
  }
  const double nrm = 1.0 / sqrt(3472.0);
  return (isI ? accI : accR) * nrm;
}

__device__ double dt_val(int kk, int wq) {
  // DtT[wq][kk]: kk<32 -> DtR[v=kk][wq], kk>=32 -> DtI[v=kk-32][wq]
  const int v = (kk < 32) ? kk : kk - 32;
  const bool isI = kk >= 32;
  const double ks = 62.0 / 56.0;
  const double src = (wq + 0.5) * ks - 0.5;
  double wsum = 0.0;
  for (int wp = 0; wp < 62; ++wp) {
    const double xx = fabs(src - (double)wp) / ks;
    if (xx < 1.0) wsum += 1.0 - xx;
  }
  const double cv = (v == 0 || v == 31) ? 1.0 : 2.0;
  double accR = 0.0, accI = 0.0;
  for (int wp = 0; wp < 62; ++wp) {
    const double xx = fabs(src - (double)wp) / ks;
    if (xx >= 1.0) continue;
    const double wgt = (1.0 - xx) / wsum;
    double cc, ss;
    if (v == 0)       { cc = 1.0; ss = 0.0; }
    else if (v == 31) { cc = (wp & 1) ? -1.0 : 1.0; ss = 0.0; }
    else {
      const int p = (v * wp) % 62;
      const double ang = 6.283185307179586476925286766559 * (double)p / 62.0;
      cc = cos(ang); ss = sin(ang);
    }
    accR += wgt * cv * cc;
    accI -= wgt * cv * ss;
  }
  const double nrm = 1.0 / sqrt(3472.0);
  return (isI ? -accI : accR) * nrm;  // note: accI accumulated with -sin -> Im part is -accI*(-1)... see below
}
// Careful: round-1 stored DtR=accR*nrm, DtI=accI*nrm with accI -= wgt*cv*ss.
// dt_val must reproduce exactly that: Re=accR*nrm, Im=accI*nrm.

__device__ double dt_val_fixed(int kk, int wq) {
  const int v = (kk < 32) ? kk : kk - 32;
  const bool isI = kk >= 32;
  const double ks = 62.0 / 56.0;
  const double src = (wq + 0.5) * ks - 0.5;
  double wsum = 0.0;
  for (int wp = 0; wp < 62; ++wp) {
    const double xx = fabs(src - (double)wp) / ks;
    if (xx < 1.0) wsum += 1.0 - xx;
  }
  const double cv = (v == 0 || v == 31) ? 1.0 : 2.0;
  double accR = 0.0, accI = 0.0;
  for (int wp = 0; wp < 62; ++wp) {
    const double xx = fabs(src - (double)wp) / ks;
    if (xx >= 1.0) continue;
    const double wgt = (1.0 - xx) / wsum;
    double cc, ss;
    if (v == 0)       { cc = 1.0; ss = 0.0; }
    else if (v == 31) { cc = (wp & 1) ? -1.0 : 1.0; ss = 0.0; }
    else {
      const int p = (v * wp) % 62;
      const double ang = 6.283185307179586476925286766559 * (double)p / 62.0;
      cc = cos(ang); ss = sin(ang);
    }
    accR += wgt * cv * cc;
    accI -= wgt * cv * ss;
  }
  const double nrm = 1.0 / sqrt(3472.0);
  return (isI ? accI : accR) * nrm;
}

__device__ __forceinline__ void emit_hilo(ushort_t* hp, ushort_t* lp, int off, double val) {
  const float fv = (float)val;
  const ushort_t h = f2bf(fv);
  const float hf = bf2f(h);
  const ushort_t l = f2bf((float)(val - (double)hf));
  hp[off] = h;
  lp[off] = l;
}

__global__ void k_const(const float* __restrict__ conv_w,
                        ushort_t* BmT_h, ushort_t* BmT_l,
                        ushort_t* FARe_h, ushort_t* FARe_l,
                        ushort_t* FAIm_h, ushort_t* FAIm_l,
                        ushort_t* FDRe_h, ushort_t* FDRe_l,
                        ushort_t* FDIm_h, ushort_t* FDIm_l,
                        ushort_t* DtT_h, ushort_t* DtT_l,
                        ushort_t* W_h, ushort_t* W_l) {
  const int idx = blockIdx.x * 256 + threadIdx.x;
  if (idx < 4096) {
    // BmT[vv][k=w], k>=56 zero
    const int vv = idx >> 6, k = idx & 63;
    const double v = (k < 56) ? bmat_val(k, vv) : 0.0;
    emit_hilo(BmT_h, BmT_l, idx, v);
  } else if (idx < 36864) {
    const int t = (idx - 4096) & 8191;
    const int which = (idx - 4096) >> 13;  // 0 FARe, 1 FAIm, 2 FDRe, 3 FDIm
    const int row = t >> 7, k = t & 127;
    double val = 0.0;
    if (row < 56 && k < 112) {
      const int h = (k < 56) ? k : k - 56;
      const double ang = 6.283185307179586476925286766559 *
                         (double)((row * h) % 56) / 56.0;
      const double c = cos(ang), s = sin(ang);
      const bool lowk = (k < 56);
      // fwd: e^{-i t} -> Re=[c|s], Im=[-s|c]; inv: e^{+i t} -> Re=[c|-s], Im=[s|c]
      if (which == 0)      val = lowk ? c : s;
      else if (which == 1) val = lowk ? -s : c;
      else if (which == 2) val = lowk ? c : -s;
      else                 val = lowk ? s : c;
    }
    ushort_t* hp = (which == 0) ? FARe_h : (which == 1) ? FAIm_h : (which == 2) ? FDRe_h : FDIm_h;
    ushort_t* lp = (which == 0) ? FARe_l : (which == 1) ? FAIm_l : (which == 2) ? FDRe_l : FDIm_l;
    emit_hilo(hp, lp, t, val);
  } else if (idx < 40960) {
    const int t = idx - 36864;
    const int w = t >> 6, kk = t & 63;
    const double v = (w < 56) ? dt_val_fixed(kk, w) : 0.0;
    emit_hilo(DtT_h, DtT_l, t, v);
  } else if (idx < 106496) {
    const int t = idx - 40960;
    emit_hilo(W_h, W_l, t, (double)conv_w[t]);
  }
}

// ---------------- GAP ----------------
__global__ __launch_bounds__(256) void k_gap(const float* __restrict__ x,
                                             float* __restrict__ ctx) {
  const int img = blockIdx.x;
  const int tid = threadIdx.x;
  const float4* p4 = (const float4*)(x + (size_t)img * 3136);
  float s = 0.f;
  for (int i = tid; i < 784; i += 256) {
    const float4 v = p4[i];
    s += v.x + v.y + v.z + v.w;
  }
  for (int off = 32; off > 0; off >>= 1) s += __shfl_down(s, off, 64);
  __shared__ float ls[4];
  if ((tid & 63) == 0) ls[tid >> 6] = s;
  __syncthreads();
  if (tid == 0) ctx[img] = (ls[0] + ls[1] + ls[2] + ls[3]) * (1.0f / 3136.0f);
}

// ---------------- fc1 + LN + ReLU ----------------
__global__ void k_mlp(const float* __restrict__ ctx, const float* __restrict__ fc1_w,
                      const float* __restrict__ fc1_b, const float* __restrict__ ln_g,
                      const float* __restrict__ ln_b, float* __restrict__ hdn) {
  const int b = blockIdx.x;
  const int j = threadIdx.x;
  __shared__ float h[16];
  if (j < 16) {
    const float* cr = ctx + b * 256;
    const float* wr = fc1_w + j * 256;
    float acc = fc1_b[j];
    for (int c0 = 0; c0 < 256; ++c0) acc = fmaf(cr[c0], wr[c0], acc);
    h[j] = acc;
  }
  __syncthreads();
  if (j < 16) {
    float mu = 0.f, m2 = 0.f;
    for (int t = 0; t < 16; ++t) { mu += h[t]; m2 += h[t] * h[t]; }
    mu *= 0.0625f; m2 *= 0.0625f;
    const float var = m2 - mu * mu;
    const float val = (h[j] - mu) / sqrtf(var + 1e-5f) * ln_g[j] + ln_b[j];
    hdn[b * 16 + j] = fmaxf(val, 0.f);
  }
}

// ---------------- fourier head + softmax ----------------
__global__ __launch_bounds__(256) void k_coeffs(const float* __restrict__ hdn,
                                                const float* __restrict__ fh_w,
                                                const float* __restrict__ fh_b,
                                                float* __restrict__ coeffs) {
  const int gid = blockIdx.x * 256 + threadIdx.x;
  const int b = gid >> 12;
  const int cm = gid & 4095;
  float hv[16];
  const float* hp = hdn + b * 16;
#pragma unroll
  for (int j = 0; j < 16; ++j) hv[j] = hp[j];
  const int row0 = cm * 8;
  float a[8];
  float mx = -1e30f;
#pragma unroll
  for (int k = 0; k < 8; ++k) {
    const float* wr = fh_w + (size_t)(row0 + k) * 16;
    float acc = fh_b[row0 + k];
#pragma unroll
    for (int j = 0; j < 16; ++j) acc = fmaf(hv[j], wr[j], acc);
    a[k] = acc;
    mx = fmaxf(mx, acc);
  }
  float s = 0.f;
#pragma unroll
  for (int k = 0; k < 8; ++k) { a[k] = expf(a[k] - mx); s += a[k]; }
  const float inv = 1.f / s;
  float* outp = coeffs + (size_t)gid * 8;
#pragma unroll
  for (int k = 0; k < 8; ++k) outp[k] = a[k] * inv;
}

// ---------------- fused spectral branch, MFMA bf16, one image per block ----------------
__global__ __launch_bounds__(256) void k_fft(
    const float* __restrict__ x, const float* __restrict__ coeffs,
    const float* __restrict__ basR, const float* __restrict__ basI,
    const ushort_t* __restrict__ BmT_h, const ushort_t* __restrict__ BmT_l,
    const ushort_t* __restrict__ FARe_h, const ushort_t* __restrict__ FARe_l,
    const ushort_t* __restrict__ FAIm_h, const ushort_t* __restrict__ FAIm_l,
    const ushort_t* __restrict__ FDRe_h, const ushort_t* __restrict__ FDRe_l,
    const ushort_t* __restrict__ FDIm_h, const ushort_t* __restrict__ FDIm_l,
    const ushort_t* __restrict__ DtT_h, const ushort_t* __restrict__ DtT_l,
    ushort_t* __restrict__ ybf) {
  __shared__ __align__(16) ushort_t xa[64 * 72];    // A: x [h][w] bf16, stride 72
  __shared__ __align__(16) ushort_t x1T[32 * 136];  // B: [v][k128] Re(h)|Im(h)|pad
  __shared__ __align__(16) ushort_t x2T[32 * 136];  // B: filtered spectrum, same layout
  __shared__ __align__(16) ushort_t ta[64 * 72];    // A: T [h][Re v|Im v] stride 72
  __shared__ float gf[3584];                        // G fp32: Re [0..1792), Im [1792..)
  const int img = blockIdx.x;
  const int tid = threadIdx.x;
  const int wave = tid >> 6, lane = tid & 63, col = lane & 15, quad = lane >> 4;
  const f32x4 zf = {0.f, 0.f, 0.f, 0.f};

  // zero xa/x1T/x2T (pad regions must be 0)
  {
    unsigned int* za = (unsigned int*)xa;
    unsigned int* z1 = (unsigned int*)x1T;
    unsigned int* z2 = (unsigned int*)x2T;
    for (int i = tid; i < 2304; i += 256) za[i] = 0u;
    for (int i = tid; i < 2176; i += 256) { z1[i] = 0u; z2[i] = 0u; }
  }
  __syncthreads();

  // load x -> bf16 A-layout; compute per-image filter G (fp32)
  {
    const float4* xp = (const float4*)(x + (size_t)img * 3136);
    for (int f = tid; f < 784; f += 256) {
      const float4 v = xp[f];
      const int h = f / 14, w4 = (f % 14) * 4;
      s16x4 p;
      p[0] = (short)f2bf(v.x); p[1] = (short)f2bf(v.y);
      p[2] = (short)f2bf(v.z); p[3] = (short)f2bf(v.w);
      *(s16x4*)&xa[h * 72 + w4] = p;
    }
    const float* co = coeffs + (size_t)img * 128;
    for (int q = tid; q < 1792; q += 256) {
      const int u = q >> 5, v = q & 31;
      const int m = (u / 14) * 4 + (v >> 3);
      const float* cm = co + m * 8;
      float gr = 0.f, gi = 0.f;
#pragma unroll
      for (int k = 0; k < 8; ++k) {
        gr = fmaf(cm[k], basR[k * 1792 + q], gr);
        gi = fmaf(cm[k], basI[k * 1792 + q], gi);
      }
      gf[q] = gr;
      gf[1792 + q] = gi;
    }
  }
  __syncthreads();

  // stage b: x1 = x @ Bmat  (M=56 pad 64, N=64, K=56 pad 64)
  {
    const int mt = wave;
    const int arow = (mt * 16 + col) * 72;
    const s16x8 a0 = *(const s16x8*)&xa[arow + quad * 8];
    const s16x8 a1 = *(const s16x8*)&xa[arow + 32 + quad * 8];
    const int h0 = mt * 16 + quad * 4;
    for (int nt = 0; nt < 4; ++nt) {
      const int nrow = nt * 16 + col;  // vv
      const s16x8 bh0 = *(const s16x8*)&BmT_h[nrow * 64 + quad * 8];
      const s16x8 bl0 = *(const s16x8*)&BmT_l[nrow * 64 + quad * 8];
      const s16x8 bh1 = *(const s16x8*)&BmT_h[nrow * 64 + 32 + quad * 8];
      const s16x8 bl1 = *(const s16x8*)&BmT_l[nrow * 64 + 32 + quad * 8];
      f32x4 acc = zf;
      acc = MFMA16(a0, bh0, acc);
      acc = MFMA16(a0, bl0, acc);
      acc = MFMA16(a1, bh1, acc);
      acc = MFMA16(a1, bl1, acc);
      if (h0 < 56) {
        s16x4 p;
        p[0] = (short)f2bf(acc[0]); p[1] = (short)f2bf(acc[1]);
        p[2] = (short)f2bf(acc[2]); p[3] = (short)f2bf(acc[3]);
        const int vr = nrow & 31;
        const int kk = (nrow < 32) ? h0 : 56 + h0;
        *(s16x4*)&x1T[vr * 136 + kk] = p;
      }
    }
  }
  __syncthreads();

  // stage c: X2 = Fh_fwd @ x1 (stacked-K complex), filter by G -> x2T
  {
    const int mt = wave;
    f32x4 accRe[2] = {zf, zf}, accIm[2] = {zf, zf};
    for (int ks = 0; ks < 4; ++ks) {
      const int aoff = (mt * 16 + col) * 128 + ks * 32 + quad * 8;
      const s16x8 aRh = *(const s16x8*)&FARe_h[aoff];
      const s16x8 aRl = *(const s16x8*)&FARe_l[aoff];
      const s16x8 aIh = *(const s16x8*)&FAIm_h[aoff];
      const s16x8 aIl = *(const s16x8*)&FAIm_l[aoff];
#pragma unroll
      for (int nt = 0; nt < 2; ++nt) {
        const s16x8 b = *(const s16x8*)&x1T[(nt * 16 + col) * 136 + ks * 32 + quad * 8];
        accRe[nt] = MFMA16(aRh, b, accRe[nt]);
        accRe[nt] = MFMA16(aRl, b, accRe[nt]);
        accIm[nt] = MFMA16(aIh, b, accIm[nt]);
        accIm[nt] = MFMA16(aIl, b, accIm[nt]);
      }
    }
    const int u0 = mt * 16 + quad * 4;
    if (u0 < 56) {
#pragma unroll
      for (int nt = 0; nt < 2; ++nt) {
        const int v = nt * 16 + col;
        s16x4 pR, pI;
#pragma unroll
        for (int r = 0; r < 4; ++r) {
          const int u = u0 + r;
          const float gr = gf[u * 32 + v];
          const float gi = gf[1792 + u * 32 + v];
          const float re = accRe[nt][r] * gr - accIm[nt][r] * gi;
          const float im = accRe[nt][r] * gi + accIm[nt][r] * gr;
          pR[r] = (short)f2bf(re);
          pI[r] = (short)f2bf(im);
        }
        *(s16x4*)&x2T[v * 136 + u0] = pR;
        *(s16x4*)&x2T[v * 136 + 56 + u0] = pI;
      }
    }
  }
  __syncthreads();

  // stage d: T = Fh_inv @ X2f -> ta (A-layout for stage e)
  {
    const int mt = wave;
    f32x4 accRe[2] = {zf, zf}, accIm[2] = {zf, zf};
    for (int ks = 0; ks < 4; ++ks) {
      const int aoff = (mt * 16 + col) * 128 + ks * 32 + quad * 8;
      const s16x8 aRh = *(const s16x8*)&FDRe_h[aoff];
      const s16x8 aRl = *(const s16x8*)&FDRe_l[aoff];
      const s16x8 aIh = *(const s16x8*)&FDIm_h[aoff];
      const s16x8 aIl = *(const s16x8*)&FDIm_l[aoff];
#pragma unroll
      for (int nt = 0; nt < 2; ++nt) {
        const s16x8 b = *(const s16x8*)&x2T[(nt * 16 + col) * 136 + ks * 32 + quad * 8];
        accRe[nt] = MFMA16(aRh, b, accRe[nt]);
        accRe[nt] = MFMA16(aRl, b, accRe[nt]);
        accIm[nt] = MFMA16(aIh, b, accIm[nt]);
        accIm[nt] = MFMA16(aIl, b, accIm[nt]);
      }
    }
    const int h0 = mt * 16 + quad * 4;  // rows >=56 produce zeros (FhD rows zeroed)
#pragma unroll
    for (int nt = 0; nt < 2; ++nt) {
      const int v = nt * 16 + col;
#pragma unroll
      for (int r = 0; r < 4; ++r) {
        ta[(h0 + r) * 72 + v]      = f2bf(accRe[nt][r]);
        ta[(h0 + r) * 72 + 32 + v] = f2bf(accIm[nt][r]);
      }
    }
  }
  __syncthreads();

  // stage e: y = T @ DtStack (K=64), store bf16
  {
    const int mt = wave;
    const int arow = (mt * 16 + col) * 72;
    const s16x8 a0 = *(const s16x8*)&ta[arow + quad * 8];
    const s16x8 a1 = *(const s16x8*)&ta[arow + 32 + quad * 8];
    const int h0 = mt * 16 + quad * 4;
    ushort_t* yo = ybf + (size_t)img * 3136;
    for (int nt = 0; nt < 4; ++nt) {
      const int w = nt * 16 + col;
      const s16x8 bh0 = *(const s16x8*)&DtT_h[w * 64 + quad * 8];
      const s16x8 bl0 = *(const s16x8*)&DtT_l[w * 64 + quad * 8];
      const s16x8 bh1 = *(const s16x8*)&DtT_h[w * 64 + 32 + quad * 8];
      const s16x8 bl1 = *(const s16x8*)&DtT_l[w * 64 + 32 + quad * 8];
      f32x4 acc = zf;
      acc = MFMA16(a0, bh0, acc);
      acc = MFMA16(a0, bl0, acc);
      acc = MFMA16(a1, bh1, acc);
      acc = MFMA16(a1, bl1, acc);
      if (h0 < 56 && w < 56) {
#pragma unroll
        for (int r = 0; r < 4; ++r) yo[(h0 + r) * 56 + w] = f2bf(acc[r]);
      }
    }
  }
}

// ---------------- 1x1 conv via MFMA: A=W(hi/lo), B=y bf16 direct from global ----------------
__global__ __launch_bounds__(256) void k_conv(const ushort_t* __restrict__ ybf,
                                              const ushort_t* __restrict__ W_h,
                                              const ushort_t* __restrict__ W_l,
                                              float* __restrict__ z) {
  const int pb = blockIdx.x;   // 0..12, 256 pixels each (last ragged)
  const int oh = blockIdx.y;   // 0..1, 128 out-channels each
  const int b = blockIdx.z;
  const int tid = threadIdx.x;
  const int wave = tid >> 6, lane = tid & 63, col = lane & 15, quad = lane >> 4;
  const f32x4 zf = {0.f, 0.f, 0.f, 0.f};
  f32x4 acc[8][4];
#pragma unroll
  for (int mt = 0; mt < 8; ++mt)
#pragma unroll
    for (int i = 0; i < 4; ++i) acc[mt][i] = zf;

  const size_t ybase = (size_t)b * 256 * 3136;
  int p0i[4];
  bool act[4];
#pragma unroll
  for (int i = 0; i < 4; ++i) {
    p0i[i] = pb * 256 + (wave * 4 + i) * 16;
    act[i] = p0i[i] < 3136;
  }

  for (int ks = 0; ks < 8; ++ks) {
    const int c0 = ks * 32 + quad * 8;
    s16x8 bfr[4];
#pragma unroll
    for (int i = 0; i < 4; ++i) {
      if (act[i]) {
        s16x8 t;
#pragma unroll
        for (int j = 0; j < 8; ++j)
          t[j] = (short)ybf[ybase + (size_t)(c0 + j) * 3136 + p0i[i] + col];
        bfr[i] = t;
      }
    }
#pragma unroll
    for (int mt = 0; mt < 8; ++mt) {
      const int orow = oh * 128 + mt * 16 + col;
      const s16x8 ah = *(const s16x8*)&W_h[orow * 256 + ks * 32 + quad * 8];
      const s16x8 al = *(const s16x8*)&W_l[orow * 256 + ks * 32 + quad * 8];
#pragma unroll
      for (int i = 0; i < 4; ++i) {
        if (act[i]) {
          acc[mt][i] = MFMA16(ah, bfr[i], acc[mt][i]);
          acc[mt][i] = MFMA16(al, bfr[i], acc[mt][i]);
        }
      }
    }
  }

#pragma unroll
  for (int mt = 0; mt < 8; ++mt) {
#pragma unroll
    for (int i = 0; i < 4; ++i) {
      if (!act[i]) continue;
#pragma unroll
      for (int r = 0; r < 4; ++r) {
        const int o = oh * 128 + mt * 16 + quad * 4 + r;
        z[((size_t)b * 256 + o) * 3136 + p0i[i] + col] = acc[mt][i][r];
      }
    }
  }
}

// ---------------- BN sums over z ----------------
__global__ __launch_bounds__(256) void k_bnsum(const float* __restrict__ z,
                                               float* __restrict__ bnsum,
                                               float* __restrict__ bnsq) {
  const int bo = blockIdx.x;  // b*256+o
  const int tid = threadIdx.x;
  const float4* p4 = (const float4*)(z + (size_t)bo * 3136);
  float s = 0.f, s2 = 0.f;
  for (int i = tid; i < 784; i += 256) {
    const float4 v = p4[i];
    s += v.x + v.y + v.z + v.w;
    s2 += v.x * v.x + v.y * v.y + v.z * v.z + v.w * v.w;
  }
  for (int off = 32; off > 0; off >>= 1) {
    s += __shfl_down(s, off, 64);
    s2 += __shfl_down(s2, off, 64);
  }
  __shared__ float ls[8];
  if ((tid & 63) == 0) { ls[tid >> 6] = s; ls[4 + (tid >> 6)] = s2; }
  __syncthreads();
  if (tid == 0) {
    atomicAdd(bnsum + (bo & 255), ls[0] + ls[1] + ls[2] + ls[3]);
    atomicAdd(bnsq + (bo & 255), ls[4] + ls[5] + ls[6] + ls[7]);
  }
}

__global__ void k_bnstats(const float* __restrict__ bnsum, const float* __restrict__ bnsq,
                          const float* __restrict__ bn_g, const float* __restrict__ bn_b,
                          float* __restrict__ scale, float* __restrict__ shift) {
  const int o = threadIdx.x;
  if (o < 256) {
    const float N = 32.f * 3136.f;
    const float m = bnsum[o] / N;
    const float v = bnsq[o] / N - m * m;
    const float sc = bn_g[o] / sqrtf(v + 1e-5f);
    scale[o] = sc;
    shift[o] = bn_b[o] - m * sc;
  }
}

__global__ __launch_bounds__(256) void k_bnapply(float* __restrict__ z,
                                                 const float* __restrict__ scale,
                                                 const float* __restrict__ shift) {
  const size_t i = ((size_t)blockIdx.x * 256 + threadIdx.x) * 4;
  const int ch = (int)((i / 3136) & 255);
  const float sc = scale[ch], sh = shift[ch];
  float4 v = *(float4*)(z + i);
  v.x = fmaf(v.x, sc, sh);
  v.y = fmaf(v.y, sc, sh);
  v.z = fmaf(v.z, sc, sh);
  v.w = fmaf(v.w, sc, sh);
  *(float4*)(z + i) = v;
}

extern "C" void kernel_launch(void* const* d_in, const int* in_sizes, int n_in,
                              void* d_out, int out_size, void* d_ws, size_t ws_size,
                              hipStream_t stream) {
  const float* x          = (const float*)d_in[0];
  const float* fc1_w      = (const float*)d_in[1];
  const float* fc1_b      = (const float*)d_in[2];
  const float* ln_g       = (const float*)d_in[3];
  const float* ln_b       = (const float*)d_in[4];
  const float* fh_w       = (const float*)d_in[5];
  const float* fh_b       = (const float*)d_in[6];
  const float* basis_real = (const float*)d_in[7];
  const float* basis_imag = (const float*)d_in[8];
  const float* conv_w     = (const float*)d_in[9];
  const float* bn_g       = (const float*)d_in[10];
  const float* bn_b       = (const float*)d_in[11];
  float* out = (float*)d_out;
  char* ws = (char*)d_ws;
  (void)in_sizes; (void)n_in; (void)out_size; (void)ws_size;

  float* ctx   = (float*)(ws + WO_CTX);
  float* hdn   = (float*)(ws + WO_HDN);
  float* bnsum = (float*)(ws + WO_BNSUM);
  float* bnsq  = (float*)(ws + WO_BNSQ);
  float* scale = (float*)(ws + WO_SCALE);
  float* shift = (float*)(ws + WO_SHIFT);
  float* coef  = (float*)(ws + WO_COEF);
  ushort_t* BmT_h  = (ushort_t*)(ws + WO_BMT_H);
  ushort_t* BmT_l  = (ushort_t*)(ws + WO_BMT_L);
  ushort_t* FARe_h = (ushort_t*)(ws + WO_FARE_H);
  ushort_t* FARe_l = (ushort_t*)(ws + WO_FARE_L);
  ushort_t* FAIm_h = (ushort_t*)(ws + WO_FAIM_H);
  ushort_t* FAIm_l = (ushort_t*)(ws + WO_FAIM_L);
  ushort_t* FDRe_h = (ushort_t*)(ws + WO_FDRE_H);
  ushort_t* FDRe_l = (ushort_t*)(ws + WO_FDRE_L);
  ushort_t* FDIm_h = (ushort_t*)(ws + WO_FDIM_H);
  ushort_t* FDIm_l = (ushort_t*)(ws + WO_FDIM_L);
  ushort_t* DtT_h  = (ushort_t*)(ws + WO_DTT_H);
  ushort_t* DtT_l  = (ushort_t*)(ws + WO_DTT_L);
  ushort_t* W_h    = (ushort_t*)(ws + WO_CW_H);
  ushort_t* W_l    = (ushort_t*)(ws + WO_CW_L);
  ushort_t* ybf    = (ushort_t*)(ws + WO_YBF);

  hipMemsetAsync(bnsum, 0, 2048, stream);  // bnsum+bnsq contiguous

  hipLaunchKernelGGL(k_const, dim3(416), dim3(256), 0, stream,
                     conv_w, BmT_h, BmT_l, FARe_h, FARe_l, FAIm_h, FAIm_l,
                     FDRe_h, FDRe_l, FDIm_h, FDIm_l, DtT_h, DtT_l, W_h, W_l);
  hipLaunchKernelGGL(k_gap, dim3(8192), dim3(256), 0, stream, x, ctx);
  hipLaunchKernelGGL(k_mlp, dim3(32), dim3(64), 0, stream,
                     ctx, fc1_w, fc1_b, ln_g, ln_b, hdn);
  hipLaunchKernelGGL(k_coeffs, dim3(512), dim3(256), 0, stream, hdn, fh_w, fh_b, coef);
  hipLaunchKernelGGL(k_fft, dim3(8192), dim3(256), 0, stream,
                     x, coef, basis_real, basis_imag,
                     BmT_h, BmT_l, FARe_h, FARe_l, FAIm_h, FAIm_l,
                     FDRe_h, FDRe_l, FDIm_h, FDIm_l, DtT_h, DtT_l, ybf);
  hipLaunchKernelGGL(k_conv, dim3(13, 2, 32), dim3(256), 0, stream, ybf, W_h, W_l, out);
  hipLaunchKernelGGL(k_bnsum, dim3(8192), dim3(256), 0, stream, out, bnsum, bnsq);
  hipLaunchKernelGGL(k_bnstats, dim3(1), dim3(256), 0, stream,
                     bnsum, bnsq, bn_g, bn_b, scale, shift);
  hipLaunchKernelGGL(k_bnapply, dim3(25088), dim3(256), 0, stream, out, scale, shift);
}